// Round 1
// baseline (210.085 us; speedup 1.0000x reference)
//
#include <hip/hip_runtime.h>
#include <math.h>

#define NB 32        // batches
#define NP 512       // N == M == 512
#define RG 8         // row-groups (blocks) per batch
#define RPB 64       // rows per block
#define ITERS 50
#define EPSV   0.05f
#define INVEPS 20.0f

typedef unsigned long long u64;
typedef unsigned int u32;

// ws layout: pack[2][NB][RG][NP] u32 (row-major: each 512-col stream is a
// contiguous single-writer array -> no false sharing), then epi[NB][RG] float2.
// Poison safety: 0xAAAAAAAA low 3 bits = 2; tag set {1,3,4,5,6,7} never
// contains 2 and all tags within a 6-window are distinct. epi tag 51.0f.
#define N_PACK (2*NB*RG*NP)
#define PAR_STRIDE (NB*RG*NP)      // 131072 u32 per parity buffer

// ---- agent-scope (device-coherent, LLC) primitives — cross-XCD safe ----
__device__ __forceinline__ void st32(u32* p, u32 v) {
  __hip_atomic_store(p, v, __ATOMIC_RELAXED, __HIP_MEMORY_SCOPE_AGENT);
}
__device__ __forceinline__ u32 ld32(const u32* p) {
  return __hip_atomic_load(p, __ATOMIC_RELAXED, __HIP_MEMORY_SCOPE_AGENT);
}
__device__ __forceinline__ void st64f(float2* p, float tag, float val) {
  union { float2 f; u64 u; } c; c.f = make_float2(tag, val);
  __hip_atomic_store((u64*)p, c.u, __ATOMIC_RELAXED, __HIP_MEMORY_SCOPE_AGENT);
}
__device__ __forceinline__ float2 ld64f(const float2* p) {
  union { u64 u; float2 f; } c;
  c.u = __hip_atomic_load((const u64*)p, __ATOMIC_RELAXED, __HIP_MEMORY_SCOPE_AGENT);
  return c.f;
}

// ---- L2 fast path (R1): sc0 load bypasses the per-CU L1 but HITS the shared
// per-XCD L2. Producer's plain store is write-through L1 -> lands in that same
// L2, so same-XCD peers see it at ~L2 latency instead of LLC/HBM latency.
// The tag check + periodic agent-scope fallback make any block->XCD mapping
// safe: stale data is detected (never accepted), progress is guaranteed.
__device__ __forceinline__ void ld7_issue(
    const u32* p0, const u32* p1, const u32* p2, const u32* p3,
    const u32* p4, const u32* p5, const u32* p6,
    u32& q0, u32& q1, u32& q2, u32& q3, u32& q4, u32& q5, u32& q6) {
  asm volatile(
    "global_load_dword %0, %7, off sc0\n\t"
    "global_load_dword %1, %8, off sc0\n\t"
    "global_load_dword %2, %9, off sc0\n\t"
    "global_load_dword %3, %10, off sc0\n\t"
    "global_load_dword %4, %11, off sc0\n\t"
    "global_load_dword %5, %12, off sc0\n\t"
    "global_load_dword %6, %13, off sc0"
    : "=&v"(q0), "=&v"(q1), "=&v"(q2), "=&v"(q3),
      "=&v"(q4), "=&v"(q5), "=&v"(q6)
    : "v"(p0), "v"(p1), "v"(p2), "v"(p3), "v"(p4), "v"(p5), "v"(p6)
    : "memory");
}
__device__ __forceinline__ void ld7_l2(
    const u32* p0, const u32* p1, const u32* p2, const u32* p3,
    const u32* p4, const u32* p5, const u32* p6,
    u32& q0, u32& q1, u32& q2, u32& q3, u32& q4, u32& q5, u32& q6) {
  asm volatile(
    "global_load_dword %0, %7, off sc0\n\t"
    "global_load_dword %1, %8, off sc0\n\t"
    "global_load_dword %2, %9, off sc0\n\t"
    "global_load_dword %3, %10, off sc0\n\t"
    "global_load_dword %4, %11, off sc0\n\t"
    "global_load_dword %5, %12, off sc0\n\t"
    "global_load_dword %6, %13, off sc0\n\t"
    "s_waitcnt vmcnt(0)"
    : "=&v"(q0), "=&v"(q1), "=&v"(q2), "=&v"(q3),
      "=&v"(q4), "=&v"(q5), "=&v"(q6)
    : "v"(p0), "v"(p1), "v"(p2), "v"(p3), "v"(p4), "v"(p5), "v"(p6)
    : "memory");
}

// tag for iteration k: nibble LUT over k%6 -> {1,3,4,5,6,7}; all tags in any
// 6-window distinct, so tag(k) != tag(k-1) != tag(k-2) (stale detect exact)
__device__ __forceinline__ u32 tag_of(int k) {
  return (0x765431u >> (4 * (k % 6))) & 0xFu;
}
// pack fp32 value with tag in low 3 mantissa bits (<=7 ulp perturbation)
__device__ __forceinline__ u32 pack_slot(float v, u32 tag) {
  return (__float_as_uint(v) & ~7u) | tag;
}

// ---------------- single fused kernel: setup + 50 linear-Sinkhorn iters + ot ----
// ONE batch per 512-thread block, 64 rows each, RG=8 blocks/batch, grid=256
// (1 block/CU, all resident -> spin rendezvous deadlock-free).
// R1 change: XCD-local batches + L2-served rendezvous.
//  - blockIdx decode puts all 8 blocks of a batch at blockIdx == c (mod 8):
//    under round-robin WG->XCD dispatch they share one XCD (and its L2).
//  - publish = plain store (write-through -> shared L2) + agent store (LLC);
//    identical bits at the same address, so any writeback order is benign.
//  - poll = sc0 L2 loads; every 4th sweep agent-scope (LLC) fallback so a
//    different dispatch mapping degrades gracefully instead of hanging.
__global__ __launch_bounds__(NP) void emd_kernel(
    const float* __restrict__ a_mask, const float* __restrict__ pc_a,
    const float* __restrict__ b_mask, const float* __restrict__ pc_b,
    u32* __restrict__ pack, float2* __restrict__ epi,
    float* __restrict__ out)
{
  const int rb = blockIdx.x;
  // XCD-local decode: rb = ((rg*4 + (b>>3)) << 3) | (b&7)  => rb%8 = b%8
  const int xc = rb & 7;             // XCD id under round-robin dispatch
  const int qq = rb >> 3;            // 0..31
  const int rg = qq >> 2;            // row-group 0..7
  const int b  = ((qq & 3) << 3) | xc;  // batch 0..31 (4 batches per XCD)
  const int t  = threadIdx.x;
  const int chunk = t & 7;           // 8 threads per row
  const int lrow  = t >> 3;          // local row 0..63
  const int grow  = rg*RPB + lrow;
  const int lane  = t & 63, wid = t >> 6;

  __shared__ __align__(16) float rho_l[NP];   // exp(logv)
  __shared__ __align__(16) float bw_l[NP];    // col masses
  __shared__ __align__(16) float u_l[RPB];    // exp(logu)
  __shared__ __align__(16) float sm[NP];      // setup aw / epilogue scratch
  __shared__ float red[16];

  float4 eKreg[16];     // row slice: row=grow, cols 32*cc+4*chunk+e
  float  eKcol[RPB];    // col slice: col=t, rows rg*64+i
  float  aw_r, bw_t, hub = 0.f;

  // remote stream pointers (par=0); per-iteration add (k&1)*PAR_STRIDE
  #define RIDX(i) ((i) + ((i) >= rg ? 1 : 0))
  const u32* pbase = pack + (size_t)b*RG*NP + t;
  const u32* p0 = pbase + (size_t)RIDX(0)*NP;
  const u32* p1 = pbase + (size_t)RIDX(1)*NP;
  const u32* p2 = pbase + (size_t)RIDX(2)*NP;
  const u32* p3 = pbase + (size_t)RIDX(3)*NP;
  const u32* p4 = pbase + (size_t)RIDX(4)*NP;
  const u32* p5 = pbase + (size_t)RIDX(5)*NP;
  const u32* p6 = pbase + (size_t)RIDX(6)*NP;
  u32* ownp = pack + ((size_t)(b*RG + rg))*NP + t;

  // ================= setup: masses, huber, expK caches =================
  {
    const float apt = a_mask[b*NP+t] * pc_a[((size_t)b*NP+t)*3+2];
    const float bpt = b_mask[b*NP+t] * pc_b[((size_t)b*NP+t)*3+2];
    float ra = apt, rv = bpt;
    #pragma unroll
    for (int o = 32; o; o >>= 1) { ra += __shfl_xor(ra, o); rv += __shfl_xor(rv, o); }
    if (lane == 0) { red[wid] = ra; red[8+wid] = rv; }
    __syncthreads();
    float asum = 0.f, bsum = 0.f;
    #pragma unroll
    for (int w = 0; w < 8; ++w) { asum += red[w]; bsum += red[8+w]; }
    const float e = asum - bsum, ae = fabsf(e);
    hub = (ae <= 1.f) ? 0.5f*e*e : (ae - 0.5f);
    sm[t]   = (apt > 0.f) ? apt/asum : 0.f;   // aw
    bw_l[t] = (bpt > 0.f) ? bpt/bsum : 0.f;
    __syncthreads();
    aw_r = sm[grow];
    bw_t = bw_l[t];
    const float ax = pc_a[((size_t)b*NP+grow)*3+0];
    const float ay = pc_a[((size_t)b*NP+grow)*3+1];
    const bool  va = aw_r > 0.f;
    #pragma unroll
    for (int cc = 0; cc < 16; ++cc) {
      float r[4];
      #pragma unroll
      for (int e2 = 0; e2 < 4; ++e2) {
        const int col = 32*cc + 4*chunk + e2;
        const float bx = pc_b[((size_t)b*NP+col)*3+0];
        const float by = pc_b[((size_t)b*NP+col)*3+1];
        const bool  vb = bw_l[col] > 0.f;
        const float dx = ax-bx, dy = ay-by;
        const float d  = sqrtf(dx*dx + dy*dy + 1e-12f);
        r[e2] = (va && vb) ? __expf((-INVEPS)*d) : 1.f;   // K=0 for masked pairs
      }
      eKreg[cc] = make_float4(r[0], r[1], r[2], r[3]);
    }
    const float bx0 = pc_b[((size_t)b*NP+t)*3+0];
    const float by0 = pc_b[((size_t)b*NP+t)*3+1];
    const bool  vb0 = bw_t > 0.f;
    #pragma unroll
    for (int i = 0; i < RPB; ++i) {
      const int row = rg*RPB + i;
      const float axi = pc_a[((size_t)b*NP+row)*3+0];  // wave-uniform -> scalar loads
      const float ayi = pc_a[((size_t)b*NP+row)*3+1];
      const bool  vai = sm[row] > 0.f;
      const float dx = axi-bx0, dy = ayi-by0;
      const float d  = sqrtf(dx*dx + dy*dy + 1e-12f);
      eKcol[i] = (vai && vb0) ? __expf((-INVEPS)*d) : 1.f;
    }
    rho_l[t] = 1.f;     // rho(0) = exp(logv=0) = 1
    __syncthreads();
  }

  // ================= main loop =================
  for (int k = 1; k <= ITERS; ++k) {
    const u32 tag = tag_of(k);
    const size_t po = (size_t)(k & 1) * (size_t)PAR_STRIDE;
    u32 q0, q1, q2, q3, q4, q5, q6;

    // ---- speculative early issue (sc0/L2) of the 7 remote streams for THIS
    // iteration; results consumed in A after an explicit vmcnt wait.
    ld7_issue(p0+po, p1+po, p2+po, p3+po, p4+po, p5+po, p6+po,
              q0, q1, q2, q3, q4, q5, q6);

    // ---- B: u(k) = aw / sum_j ek*rho(k-1)
    {
      const float4* r4p = (const float4*)rho_l;
      float dot = 0.f;
      #pragma unroll
      for (int cc = 0; cc < 16; ++cc) {
        const float4 g4 = r4p[8*cc + chunk];
        const float4 kk = eKreg[cc];
        dot += kk.x*g4.x + kk.y*g4.y + kk.z*g4.z + kk.w*g4.w;
      }
      #pragma unroll
      for (int o = 4; o; o >>= 1) dot += __shfl_xor(dot, o);   // 8-lane row reduce
      if (chunk == 0) u_l[lrow] = aw_r / fmaxf(dot, 1e-38f);
    }
    __syncthreads();   // u_l ready (also: all rho_l reads done)

    // ---- C: publish packed col partial s(k) for col t; keep own value local
    float sc_own;
    {
      const float4* u4p = (const float4*)u_l;
      float sc = 0.f;
      #pragma unroll
      for (int i4 = 0; i4 < 16; ++i4) {
        const float4 uu = u4p[i4];
        sc += eKcol[4*i4+0]*uu.x + eKcol[4*i4+1]*uu.y
            + eKcol[4*i4+2]*uu.z + eKcol[4*i4+3]*uu.w;
      }
      sc_own = sc;
      const u32 w = pack_slot(sc, tag);
      u32* os = ownp + po;
      // dual publish: plain store -> write-through L1 -> shared per-XCD L2
      // (fast path for same-XCD peers), then agent store -> LLC (fallback
      // path, cross-XCD safe). Same address, same bits -> order-benign.
      asm volatile("global_store_dword %0, %1, off" :: "v"(os), "v"(w) : "memory");
      st32(os, w);
    }

    // ---- A: wait speculative loads (vmcnt(2): the 2 newest vmem ops are our
    // publish stores — don't stall on their acks, peers consume them), then
    // gang re-poll at L2; every 4th sweep agent-scope (LLC) for progress
    // under any block->XCD mapping.
    {
      asm volatile("s_waitcnt vmcnt(2)" ::: "memory");
      __builtin_amdgcn_sched_barrier(0);
      int sweeps = 0;
      while (true) {
        const u32 bad = ((q0 & 7u) ^ tag) | ((q1 & 7u) ^ tag)
                      | ((q2 & 7u) ^ tag) | ((q3 & 7u) ^ tag)
                      | ((q4 & 7u) ^ tag) | ((q5 & 7u) ^ tag)
                      | ((q6 & 7u) ^ tag);
        if (!bad) break;
        ++sweeps;
        if ((sweeps & 3) == 0) {
          // LLC fallback: bypasses (possibly stale) local L2
          q0 = ld32(p0+po); q1 = ld32(p1+po); q2 = ld32(p2+po);
          q3 = ld32(p3+po); q4 = ld32(p4+po); q5 = ld32(p5+po);
          q6 = ld32(p6+po);
        } else {
          ld7_l2(p0+po, p1+po, p2+po, p3+po, p4+po, p5+po, p6+po,
                 q0, q1, q2, q3, q4, q5, q6);
        }
        if (sweeps > (1<<24)) break;    // fail visibly, never hang
      }
      float S = sc_own
              + __uint_as_float(q0) + __uint_as_float(q1) + __uint_as_float(q2)
              + __uint_as_float(q3) + __uint_as_float(q4) + __uint_as_float(q5)
              + __uint_as_float(q6);                      // <=7 ulp tag noise
      rho_l[t] = bw_t / fmaxf(S, 1e-38f);
    }
    __syncthreads();   // rho_l(k) ready for next B / epilogue
  }

  // ---- epilogue: ot partial = sum d^2 * u_i * ek * rho_j over my row slice
  float acc = 0.f;
  {
    const float ur = u_l[lrow];                  // u(50)
    const float4* r4p = (const float4*)rho_l;    // rho(50)
    #pragma unroll
    for (int cc = 0; cc < 16; ++cc) {
      const float4 g4 = r4p[8*cc + chunk];
      const float4 kk = eKreg[cc];
      const float ek[4] = {kk.x, kk.y, kk.z, kk.w};
      const float vv[4] = {g4.x, g4.y, g4.z, g4.w};
      #pragma unroll
      for (int e2 = 0; e2 < 4; ++e2) {
        const float lk = __logf(fmaxf(ek[e2], 1e-38f));  // d = -EPS*lk; masked: lk=0 -> d2=0
        const float d2 = (EPSV*lk)*(EPSV*lk);
        const float v  = d2 * ur * ek[e2] * vv[e2];
        acc += (ek[e2] > 0.f) ? v : 0.f;
      }
    }
  }
  // block-reduce, publish tagged epi, rg==0 gathers
  sm[t] = acc;
  __syncthreads();
  if (t < 64) {
    float v = 0.f;
    #pragma unroll
    for (int q = 0; q < 8; ++q) v += sm[t*8+q];
    #pragma unroll
    for (int o = 32; o; o >>= 1) v += __shfl_xor(v, o);
    if (t == 0) st64f(epi + (size_t)b*RG + rg, 51.f, v);
  }
  if (rg == 0 && t < RG) {     // gather: 8 lanes, poll + shfl-reduce
    float2 pr;
    long long spins = 0;
    do {
      pr = ld64f(epi + (size_t)b*RG + t);
      if (pr.x == 51.f) break;
      __builtin_amdgcn_s_sleep(1);
    } while (++spins < (1LL<<27));
    float v = pr.y;
    #pragma unroll
    for (int o = 4; o; o >>= 1) v += __shfl_xor(v, o);
    if (t == 0) out[b] = v + hub;
  }
}

extern "C" void kernel_launch(void* const* d_in, const int* in_sizes, int n_in,
                              void* d_out, int out_size, void* d_ws, size_t ws_size,
                              hipStream_t stream) {
  const float* a_mask = (const float*)d_in[0];
  const float* pc_a   = (const float*)d_in[1];
  const float* b_mask = (const float*)d_in[2];
  const float* pc_b   = (const float*)d_in[3];
  float* out = (float*)d_out;
  u32*    pack = (u32*)d_ws;                 // 1 MiB
  float2* epi  = (float2*)(pack + N_PACK);   // + 2 KiB
  (void)in_sizes; (void)n_in; (void)out_size; (void)ws_size;

  emd_kernel<<<NB*RG, NP, 0, stream>>>(a_mask, pc_a, b_mask, pc_b,
                                       pack, epi, out);
}